// Round 1
// baseline (576.363 us; speedup 1.0000x reference)
//
#include <hip/hip_runtime.h>

#define DIM_IN 128
#define DIM_HID 256
#define DIM_OUT 128
#define N_DIST 1024

// ws layout (bytes):
// [0,     4096): counts[1024]  (zeroed via hipMemsetAsync)
// [4096,  8192): offsets[1024]
// [8192, 12288): cursor[1024]
// [12288,12292): is64 flag
// [16384, ... ): sorted node indices [N] int32  (~2 MB)

__global__ void detect_kernel(const int* __restrict__ zone_raw, int* __restrict__ flag) {
    // If zone_lst is int64, the high 32-bit word of each element is 0.
    // If int32, "odd words" are real values in [0,1024); all-zero is ~impossible.
    bool is64 = true;
    for (int i = 0; i < 64; i++) {
        if (zone_raw[2 * i + 1] != 0) { is64 = false; break; }
    }
    *flag = is64 ? 1 : 0;
}

__global__ void hist_kernel(const int* __restrict__ zone, int n,
                            int* __restrict__ counts, const int* __restrict__ flag) {
    const int is64 = *flag;
    int i = blockIdx.x * blockDim.x + threadIdx.x;
    const int stride = gridDim.x * blockDim.x;
    const long long* zone64 = (const long long*)zone;
    for (; i < n; i += stride) {
        int z = is64 ? (int)zone64[i] : zone[i];
        atomicAdd(&counts[z], 1);
    }
}

__global__ void scan_kernel(const int* __restrict__ counts,
                            int* __restrict__ offsets, int* __restrict__ cursor) {
    __shared__ int tmp[N_DIST];
    const int t = threadIdx.x;
    const int v = counts[t];
    tmp[t] = v;
    __syncthreads();
    for (int off = 1; off < N_DIST; off <<= 1) {
        int add = (t >= off) ? tmp[t - off] : 0;
        __syncthreads();
        tmp[t] += add;
        __syncthreads();
    }
    const int excl = tmp[t] - v;   // exclusive prefix
    offsets[t] = excl;
    cursor[t] = excl;
}

__global__ void scatter_kernel(const int* __restrict__ zone, int n,
                               int* __restrict__ cursor, int* __restrict__ sorted,
                               const int* __restrict__ flag) {
    const int is64 = *flag;
    int i = blockIdx.x * blockDim.x + threadIdx.x;
    const int stride = gridDim.x * blockDim.x;
    const long long* zone64 = (const long long*)zone;
    for (; i < n; i += stride) {
        int z = is64 ? (int)zone64[i] : zone[i];
        int pos = atomicAdd(&cursor[z], 1);
        sorted[pos] = i;
    }
}

// One block per district: gather rows (float4 x 32 lanes, 8 node-groups),
// reduce to head[128], then fused MLP: relu -> @w1+b1 -> relu -> @w2+b2.
__global__ __launch_bounds__(256)
void district_kernel(const float* __restrict__ x, const int* __restrict__ sorted,
                     const int* __restrict__ offsets, const int* __restrict__ counts,
                     const float* __restrict__ w1, const float* __restrict__ b1,
                     const float* __restrict__ w2, const float* __restrict__ b2,
                     float* __restrict__ out) {
    const int d = blockIdx.x;
    const int start = offsets[d];
    const int cnt = counts[d];
    const int t = threadIdx.x;
    const int q = t & 31;   // 4-float chunk index: dims [4q, 4q+4)
    const int g = t >> 5;   // node group 0..7

    const float* xq = x + (size_t)q * 4;
    float4 a0 = make_float4(0.f, 0.f, 0.f, 0.f);
    float4 a1 = a0, a2 = a0, a3 = a0;

    int n = g;
    // 4-deep unroll for memory-level parallelism (4 outstanding float4 loads)
    for (; n + 24 < cnt; n += 32) {
        int i0 = sorted[start + n];
        int i1 = sorted[start + n + 8];
        int i2 = sorted[start + n + 16];
        int i3 = sorted[start + n + 24];
        float4 v0 = *(const float4*)(xq + (size_t)i0 * DIM_IN);
        float4 v1 = *(const float4*)(xq + (size_t)i1 * DIM_IN);
        float4 v2 = *(const float4*)(xq + (size_t)i2 * DIM_IN);
        float4 v3 = *(const float4*)(xq + (size_t)i3 * DIM_IN);
        a0.x += v0.x; a0.y += v0.y; a0.z += v0.z; a0.w += v0.w;
        a1.x += v1.x; a1.y += v1.y; a1.z += v1.z; a1.w += v1.w;
        a2.x += v2.x; a2.y += v2.y; a2.z += v2.z; a2.w += v2.w;
        a3.x += v3.x; a3.y += v3.y; a3.z += v3.z; a3.w += v3.w;
    }
    for (; n < cnt; n += 8) {
        int i0 = sorted[start + n];
        float4 v0 = *(const float4*)(xq + (size_t)i0 * DIM_IN);
        a0.x += v0.x; a0.y += v0.y; a0.z += v0.z; a0.w += v0.w;
    }
    a0.x += a1.x + a2.x + a3.x;
    a0.y += a1.y + a2.y + a3.y;
    a0.z += a1.z + a2.z + a3.z;
    a0.w += a1.w + a2.w + a3.w;

    __shared__ float part[8][DIM_IN];
    part[g][q * 4 + 0] = a0.x;
    part[g][q * 4 + 1] = a0.y;
    part[g][q * 4 + 2] = a0.z;
    part[g][q * 4 + 3] = a0.w;
    __syncthreads();

    __shared__ float hrelu[DIM_IN];
    if (t < DIM_IN) {
        float s = 0.f;
#pragma unroll
        for (int gg = 0; gg < 8; gg++) s += part[gg][t];
        hrelu[t] = fmaxf(s, 0.f);
    }
    __syncthreads();

    // h1[t] = relu(b1[t] + sum_k hrelu[k] * w1[k,t]);  w1 row-major [128,256]
    float s1 = b1[t];
#pragma unroll 8
    for (int k = 0; k < DIM_IN; k++) {
        s1 = fmaf(hrelu[k], w1[k * DIM_HID + t], s1);
    }
    __shared__ float h1[DIM_HID];
    h1[t] = fmaxf(s1, 0.f);
    __syncthreads();

    // out[d,t] = b2[t] + sum_j h1[j] * w2[j,t];  w2 row-major [256,128]
    if (t < DIM_OUT) {
        float s2 = b2[t];
#pragma unroll 8
        for (int j = 0; j < DIM_HID; j++) {
            s2 = fmaf(h1[j], w2[j * DIM_OUT + t], s2);
        }
        out[d * DIM_OUT + t] = s2;
    }
}

extern "C" void kernel_launch(void* const* d_in, const int* in_sizes, int n_in,
                              void* d_out, int out_size, void* d_ws, size_t ws_size,
                              hipStream_t stream) {
    const float* x   = (const float*)d_in[0];
    const int*   zone = (const int*)d_in[1];
    const float* w1  = (const float*)d_in[2];
    const float* b1  = (const float*)d_in[3];
    const float* w2  = (const float*)d_in[4];
    const float* b2  = (const float*)d_in[5];
    float* out = (float*)d_out;
    const int n = in_sizes[0] / DIM_IN;   // 500000 nodes

    char* ws = (char*)d_ws;
    int* counts  = (int*)(ws);
    int* offsets = (int*)(ws + 4096);
    int* cursor  = (int*)(ws + 8192);
    int* flag    = (int*)(ws + 12288);
    int* sorted  = (int*)(ws + 16384);

    hipMemsetAsync(counts, 0, 4096, stream);
    detect_kernel<<<1, 1, 0, stream>>>(zone, flag);
    hist_kernel<<<512, 256, 0, stream>>>(zone, n, counts, flag);
    scan_kernel<<<1, N_DIST, 0, stream>>>(counts, offsets, cursor);
    scatter_kernel<<<512, 256, 0, stream>>>(zone, n, cursor, sorted, flag);
    district_kernel<<<N_DIST, 256, 0, stream>>>(x, sorted, offsets, counts,
                                                w1, b1, w2, b2, out);
}

// Round 2
// 408.497 us; speedup vs baseline: 1.4109x; 1.4109x over previous
//
#include <hip/hip_runtime.h>

#define DIM_IN 128
#define DIM_HID 256
#define DIM_OUT 128
#define N_DIST 1024
#define NB 256          // blocks for hist/scatter (chunked counting sort)

// ws layout (bytes):
// [0,      4096): counts[1024]
// [4096,   8192): offsets[1024]
// [65536, 65536+1MB): blockHist / blockStart  [NB][N_DIST] int32
// [2MB,    4MB): sorted node indices [N] int32
//
// No global atomics anywhere: deterministic counting sort.

__device__ __forceinline__ int detect_is64(const int* __restrict__ zone_raw,
                                           int t, int* s_flag) {
    // int64 zone_lst => high words all zero. Checked by wave 0 via ballot.
    if (t < 64) {
        bool hi_zero = (zone_raw[2 * t + 1] == 0);
        unsigned long long m = __ballot(hi_zero);
        if (t == 0) *s_flag = (m == ~0ull) ? 1 : 0;
    }
    __syncthreads();
    return *s_flag;
}

__global__ __launch_bounds__(256)
void hist_kernel(const int* __restrict__ zone, int n,
                 int* __restrict__ blockHist) {
    __shared__ int lhist[N_DIST];
    __shared__ int s_is64;
    const int t = threadIdx.x;
    const int b = blockIdx.x;
    for (int i = t; i < N_DIST; i += 256) lhist[i] = 0;
    const int is64 = detect_is64(zone, t, &s_is64);

    const int chunk = (n + NB - 1) / NB;
    const int start = b * chunk;
    const int end = min(n, start + chunk);
    const long long* zone64 = (const long long*)zone;
    for (int i = start + t; i < end; i += 256) {
        int z = is64 ? (int)zone64[i] : zone[i];
        atomicAdd(&lhist[z], 1);            // LDS atomic, ~4-way avg contention
    }
    __syncthreads();
    for (int i = t; i < N_DIST; i += 256) blockHist[b * N_DIST + i] = lhist[i];
}

// One block, 1024 threads. Produces counts[d], offsets[d] (global exclusive),
// and rewrites blockHist[b][d] into blockStart[b][d] (per-block write base).
__global__ __launch_bounds__(1024)
void scan_kernel(int* __restrict__ blockHist,
                 int* __restrict__ offsets, int* __restrict__ counts) {
    __shared__ int tmp[N_DIST];
    const int d = threadIdx.x;
    int c = 0;
#pragma unroll 8
    for (int b = 0; b < NB; b++) c += blockHist[b * N_DIST + d];
    counts[d] = c;
    tmp[d] = c;
    __syncthreads();
    for (int off = 1; off < N_DIST; off <<= 1) {
        int add = (d >= off) ? tmp[d - off] : 0;
        __syncthreads();
        tmp[d] += add;
        __syncthreads();
    }
    const int excl = tmp[d] - c;
    offsets[d] = excl;
    int run = excl;
    for (int b = 0; b < NB; b++) {
        int v = blockHist[b * N_DIST + d];
        blockHist[b * N_DIST + d] = run;
        run += v;
    }
}

__global__ __launch_bounds__(256)
void scatter_kernel(const int* __restrict__ zone, int n,
                    const int* __restrict__ blockStart,
                    int* __restrict__ sorted) {
    __shared__ int lcur[N_DIST];
    __shared__ int s_is64;
    const int t = threadIdx.x;
    const int b = blockIdx.x;
    for (int i = t; i < N_DIST; i += 256) lcur[i] = blockStart[b * N_DIST + i];
    const int is64 = detect_is64(zone, t, &s_is64);

    const int chunk = (n + NB - 1) / NB;
    const int start = b * chunk;
    const int end = min(n, start + chunk);
    const long long* zone64 = (const long long*)zone;
    for (int i = start + t; i < end; i += 256) {
        int z = is64 ? (int)zone64[i] : zone[i];
        int pos = atomicAdd(&lcur[z], 1);   // LDS atomic only
        sorted[pos] = i;
    }
}

// One block per district: gather rows (float4 x 32 lanes, 8 node-groups),
// reduce to head[128], then fused MLP: relu -> @w1+b1 -> relu -> @w2+b2.
__global__ __launch_bounds__(256)
void district_kernel(const float* __restrict__ x, const int* __restrict__ sorted,
                     const int* __restrict__ offsets, const int* __restrict__ counts,
                     const float* __restrict__ w1, const float* __restrict__ b1,
                     const float* __restrict__ w2, const float* __restrict__ b2,
                     float* __restrict__ out) {
    const int d = blockIdx.x;
    const int start = offsets[d];
    const int cnt = counts[d];
    const int t = threadIdx.x;
    const int q = t & 31;   // 4-float chunk index: dims [4q, 4q+4)
    const int g = t >> 5;   // node group 0..7

    const float* xq = x + (size_t)q * 4;
    float4 a0 = make_float4(0.f, 0.f, 0.f, 0.f);
    float4 a1 = a0, a2 = a0, a3 = a0;

    int n = g;
    for (; n + 24 < cnt; n += 32) {
        int i0 = sorted[start + n];
        int i1 = sorted[start + n + 8];
        int i2 = sorted[start + n + 16];
        int i3 = sorted[start + n + 24];
        float4 v0 = *(const float4*)(xq + (size_t)i0 * DIM_IN);
        float4 v1 = *(const float4*)(xq + (size_t)i1 * DIM_IN);
        float4 v2 = *(const float4*)(xq + (size_t)i2 * DIM_IN);
        float4 v3 = *(const float4*)(xq + (size_t)i3 * DIM_IN);
        a0.x += v0.x; a0.y += v0.y; a0.z += v0.z; a0.w += v0.w;
        a1.x += v1.x; a1.y += v1.y; a1.z += v1.z; a1.w += v1.w;
        a2.x += v2.x; a2.y += v2.y; a2.z += v2.z; a2.w += v2.w;
        a3.x += v3.x; a3.y += v3.y; a3.z += v3.z; a3.w += v3.w;
    }
    for (; n < cnt; n += 8) {
        int i0 = sorted[start + n];
        float4 v0 = *(const float4*)(xq + (size_t)i0 * DIM_IN);
        a0.x += v0.x; a0.y += v0.y; a0.z += v0.z; a0.w += v0.w;
    }
    a0.x += a1.x + a2.x + a3.x;
    a0.y += a1.y + a2.y + a3.y;
    a0.z += a1.z + a2.z + a3.z;
    a0.w += a1.w + a2.w + a3.w;

    __shared__ float part[8][DIM_IN];
    part[g][q * 4 + 0] = a0.x;
    part[g][q * 4 + 1] = a0.y;
    part[g][q * 4 + 2] = a0.z;
    part[g][q * 4 + 3] = a0.w;
    __syncthreads();

    __shared__ float hrelu[DIM_IN];
    if (t < DIM_IN) {
        float s = 0.f;
#pragma unroll
        for (int gg = 0; gg < 8; gg++) s += part[gg][t];
        hrelu[t] = fmaxf(s, 0.f);
    }
    __syncthreads();

    // h1[t] = relu(b1[t] + sum_k hrelu[k] * w1[k,t]);  w1 row-major [128,256]
    float s1 = b1[t];
#pragma unroll 8
    for (int k = 0; k < DIM_IN; k++) {
        s1 = fmaf(hrelu[k], w1[k * DIM_HID + t], s1);
    }
    __shared__ float h1[DIM_HID];
    h1[t] = fmaxf(s1, 0.f);
    __syncthreads();

    // out[d,t] = b2[t] + sum_j h1[j] * w2[j,t];  w2 row-major [256,128]
    if (t < DIM_OUT) {
        float s2 = b2[t];
#pragma unroll 8
        for (int j = 0; j < DIM_HID; j++) {
            s2 = fmaf(h1[j], w2[j * DIM_OUT + t], s2);
        }
        out[d * DIM_OUT + t] = s2;
    }
}

extern "C" void kernel_launch(void* const* d_in, const int* in_sizes, int n_in,
                              void* d_out, int out_size, void* d_ws, size_t ws_size,
                              hipStream_t stream) {
    const float* x    = (const float*)d_in[0];
    const int*   zone = (const int*)d_in[1];
    const float* w1   = (const float*)d_in[2];
    const float* b1   = (const float*)d_in[3];
    const float* w2   = (const float*)d_in[4];
    const float* b2   = (const float*)d_in[5];
    float* out = (float*)d_out;
    const int n = in_sizes[0] / DIM_IN;   // 500000 nodes

    char* ws = (char*)d_ws;
    int* counts    = (int*)(ws);
    int* offsets   = (int*)(ws + 4096);
    int* blockHist = (int*)(ws + 65536);
    int* sorted    = (int*)(ws + (2u << 20));

    hist_kernel<<<NB, 256, 0, stream>>>(zone, n, blockHist);
    scan_kernel<<<1, N_DIST, 0, stream>>>(blockHist, offsets, counts);
    scatter_kernel<<<NB, 256, 0, stream>>>(zone, n, blockHist, sorted);
    district_kernel<<<N_DIST, 256, 0, stream>>>(x, sorted, offsets, counts,
                                                w1, b1, w2, b2, out);
}